// Round 4
// baseline (47.344 us; speedup 1.0000x reference)
//
#include <hip/hip_runtime.h>
#include <stdint.h>

#define RANKS 8
#define MDIM 8192   // B*T*D / 1024 rows
#define KDIM 1024
#define NDIM 1024
#define BM 256
#define BN 128
#define BK 64
#define NT (KDIM / BK)   // 16
#define THREADS 512

typedef __bf16 bf16x8 __attribute__((ext_vector_type(8)));
typedef unsigned short u16x8 __attribute__((ext_vector_type(8)));
typedef float f32x4 __attribute__((ext_vector_type(4)));

__device__ __forceinline__ unsigned short f2bf(float f) {
  union { float f; uint32_t u; } v; v.f = f;
  uint32_t u = v.u;
  u += 0x7FFFu + ((u >> 16) & 1u);   // round-to-nearest-even
  return (unsigned short)(u >> 16);
}

// Hamilton block tables
__constant__ int   c_comp[4][4] = {{0,1,2,3},{1,0,3,2},{2,3,0,1},{3,2,1,0}};
__constant__ float c_sign[4][4] = {{1.f,-1.f,-1.f,-1.f},
                                   {1.f, 1.f,-1.f, 1.f},
                                   {1.f, 1.f, 1.f,-1.f},
                                   {1.f,-1.f, 1.f, 1.f}};

// ---------------------------------------------------------------------------
// W[p][q] = sum_r H[r,k,s] * fB[r,j,i],  p = k*64+j, q = s*64+i.  bf16 out.
// ---------------------------------------------------------------------------
__global__ void build_W(const float* __restrict__ A, const float* __restrict__ fB,
                        unsigned short* __restrict__ W) {
  int idx = blockIdx.x * 256 + threadIdx.x;
  int p  = idx >> 8;
  int q4 = (idx & 255) << 2;
  int k = p >> 6, j = p & 63;
  int kb = k >> 2, ks = k & 3;
  int s = q4 >> 6;
  int sb = s >> 2, ss = s & 3;
  int   comp = c_comp[kb][sb];
  float sgn  = c_sign[kb][sb];
  float o0 = 0.f, o1 = 0.f, o2 = 0.f, o3 = 0.f;
  int i0 = q4 & 63;
#pragma unroll
  for (int r = 0; r < RANKS; ++r) {
    float h = sgn * A[r * 64 + comp * 16 + ks * 4 + ss];
    const float* fb = fB + r * 4096 + j * 64 + i0;
    o0 += h * fb[0]; o1 += h * fb[1]; o2 += h * fb[2]; o3 += h * fb[3];
  }
  ushort4 st;
  st.x = f2bf(o0); st.y = f2bf(o1); st.z = f2bf(o2); st.w = f2bf(o3);
  *reinterpret_cast<ushort4*>(W + (size_t)p * KDIM + q4) = st;
}

// ---------------------------------------------------------------------------
// Fused 8-phase GEMM (m201 template): out = bf16(x) * W^T + bias
// ---------------------------------------------------------------------------
__device__ __forceinline__ void gload16(const unsigned short* g, unsigned short* l) {
  __builtin_amdgcn_global_load_lds(
      (const __attribute__((address_space(1))) unsigned int*)(uintptr_t)g,
      (__attribute__((address_space(3))) unsigned int*)(uintptr_t)l,
      16, 0, 0);
}

#define SWZ(r, cbyte) (((r) * 128) + ((cbyte) ^ (((r) & 7) << 4)))

__global__ __launch_bounds__(THREADS, 2) void gemm_ham(
    const float* __restrict__ x, const unsigned short* __restrict__ W,
    const float* __restrict__ bias, float* __restrict__ out) {
  __shared__ unsigned short Asm_[2][BM * BK];   // 64 KB double buffer
  __shared__ unsigned short Bsm_[3][BN * BK];   // 48 KB 3-slot ring

  const int tid  = threadIdx.x;
  const int lane = tid & 63;
  const int wid  = tid >> 6;
  const int wr   = wid >> 1;        // 0..3 (M)
  const int wc   = wid & 1;         // 0..1 (N)
  const int rb   = lane & 15;
  const int qtr  = lane >> 4;

  // T1: XCD-chunked swizzle; each bx's 8 column-sharers land on one XCD.
  const int flat = blockIdx.x;
  const int xg = flat & 7, ig = flat >> 3;
  const int bx = xg * 4 + (ig >> 3);   // 0..31
  const int by = ig & 7;               // 0..7
  const int row0 = bx * BM;
  const int col0 = by * BN;

  f32x4 acc[4][4];
  f32x4 zero = {0.f, 0.f, 0.f, 0.f};
#pragma unroll
  for (int m = 0; m < 4; ++m)
#pragma unroll
    for (int n = 0; n < 4; ++n) acc[m][n] = zero;

  float4 arE[8], arO[8];   // A staging banks (even/odd tiles), static-indexed

  auto loadAg = [&](int kt, int g, float4& r0, float4& r1) {
    int id = g * 512 + tid;
    int r = id >> 3, c8 = (id & 7) << 3;
    const float* src = x + (size_t)(row0 + r) * KDIM + kt * BK + c8;
    r0 = *reinterpret_cast<const float4*>(src);
    r1 = *reinterpret_cast<const float4*>(src + 4);
  };
  auto writeAg = [&](unsigned short* dst, int g, const float4& r0, const float4& r1) {
    int id = g * 512 + tid;
    int r = id >> 3, c8 = (id & 7) << 3;
    bf16x8 v;
    v[0] = (__bf16)r0.x; v[1] = (__bf16)r0.y; v[2] = (__bf16)r0.z; v[3] = (__bf16)r0.w;
    v[4] = (__bf16)r1.x; v[5] = (__bf16)r1.y; v[6] = (__bf16)r1.z; v[7] = (__bf16)r1.w;
    *reinterpret_cast<bf16x8*>(reinterpret_cast<char*>(dst) + SWZ(r, c8 * 2)) = v;
  };
  auto stageBg = [&](int kt, unsigned short* dst, int g) {
    int id = g * 512 + tid;
    int r = id >> 3, ct = id & 7;
    // linear LDS dest + inverse-swizzled global source (rule 21)
    gload16(W + (size_t)(col0 + r) * KDIM + kt * BK + ((ct ^ (r & 7)) << 3),
            dst + id * 8);
  };

  // one phase: frag ds_reads + staging issues | barrier | lgkm0 | 16 MFMA | (caller barrier)
  auto do_phase = [&](const unsigned short* Ard, const unsigned short* Brd, int kk,
                      auto&& stg) {
    bf16x8 af[4], bfr[4];
    const int cb = qtr * 16 + kk * 64;
#pragma unroll
    for (int m = 0; m < 4; ++m)
      af[m] = *reinterpret_cast<const bf16x8*>(
          reinterpret_cast<const char*>(Ard) + SWZ(wr * 64 + m * 16 + rb, cb));
#pragma unroll
    for (int n = 0; n < 4; ++n)
      bfr[n] = *reinterpret_cast<const bf16x8*>(
          reinterpret_cast<const char*>(Brd) + SWZ(wc * 64 + n * 16 + rb, cb));
    stg();
    __builtin_amdgcn_sched_barrier(0);
    __builtin_amdgcn_s_barrier();
    asm volatile("s_waitcnt lgkmcnt(0)" ::: "memory");
    __builtin_amdgcn_sched_barrier(0);
    __builtin_amdgcn_s_setprio(1);
#pragma unroll
    for (int m = 0; m < 4; ++m)
#pragma unroll
      for (int n = 0; n < 4; ++n)
        acc[m][n] = __builtin_amdgcn_mfma_f32_16x16x32_bf16(af[m], bfr[n], acc[m][n], 0, 0, 0);
    __builtin_amdgcn_s_setprio(0);
    __builtin_amdgcn_sched_barrier(0);
  };

  // ---- prologue: A(0),A(1) via regs -> LDS; B(0),B(1) via gload_lds -------
  loadAg(0, 0, arE[0], arE[1]); loadAg(0, 1, arE[2], arE[3]);
  loadAg(0, 2, arE[4], arE[5]); loadAg(0, 3, arE[6], arE[7]);
  loadAg(1, 0, arO[0], arO[1]); loadAg(1, 1, arO[2], arO[3]);
  loadAg(1, 2, arO[4], arO[5]); loadAg(1, 3, arO[6], arO[7]);
  stageBg(0, &Bsm_[0][0], 0); stageBg(0, &Bsm_[0][0], 1);
  stageBg(1, &Bsm_[1][0], 0); stageBg(1, &Bsm_[1][0], 1);
  writeAg(&Asm_[0][0], 0, arE[0], arE[1]); writeAg(&Asm_[0][0], 1, arE[2], arE[3]);
  writeAg(&Asm_[0][0], 2, arE[4], arE[5]); writeAg(&Asm_[0][0], 3, arE[6], arE[7]);
  writeAg(&Asm_[1][0], 0, arO[0], arO[1]); writeAg(&Asm_[1][0], 1, arO[2], arO[3]);
  writeAg(&Asm_[1][0], 2, arO[4], arO[5]); writeAg(&Asm_[1][0], 3, arO[6], arO[7]);
  asm volatile("s_waitcnt vmcnt(0)" ::: "memory");
  asm volatile("s_waitcnt lgkmcnt(0)" ::: "memory");
  __builtin_amdgcn_sched_barrier(0);
  __builtin_amdgcn_s_barrier();
  __builtin_amdgcn_sched_barrier(0);

  // ---- main loop: 2 tiles per iteration (static reg banks) ----------------
  int scur = 0;
#pragma unroll 1
  for (int t = 0; t < NT; t += 2) {
    // ===== even tile t: read A slot0, load->arE (A(t+2)), write arO (A(t+1))
    {
      const unsigned short* Ard = &Asm_[0][0];
      unsigned short*       Awr = &Asm_[1][0];
      const unsigned short* Brd = &Bsm_[0][0] + scur * (BN * BK);
      int sst = scur + 2; if (sst >= 3) sst -= 3;
      unsigned short*       Bst = &Bsm_[0][0] + sst * (BN * BK);
      const bool dl = (t + 2 < NT);
      const bool dw = (t >= 1);            // t==0: A(1) was pre-written
      do_phase(Ard, Brd, 0, [&] {
        if (dl) { loadAg(t + 2, 0, arE[0], arE[1]); loadAg(t + 2, 1, arE[2], arE[3]);
                  stageBg(t + 2, Bst, 0); }
        if (dw) { writeAg(Awr, 0, arO[0], arO[1]); writeAg(Awr, 1, arO[2], arO[3]); }
      });
      __builtin_amdgcn_s_barrier();
      do_phase(Ard, Brd, 1, [&] {
        if (dl) { loadAg(t + 2, 2, arE[4], arE[5]); loadAg(t + 2, 3, arE[6], arE[7]);
                  stageBg(t + 2, Bst, 1); }
        if (dw) { writeAg(Awr, 2, arO[4], arO[5]); writeAg(Awr, 3, arO[6], arO[7]); }
      });
      if (dl) asm volatile("s_waitcnt vmcnt(10)" ::: "memory");
      else    asm volatile("s_waitcnt vmcnt(0)"  ::: "memory");
      __builtin_amdgcn_sched_barrier(0);
      __builtin_amdgcn_s_barrier();
      __builtin_amdgcn_sched_barrier(0);
      scur = scur + 1; if (scur >= 3) scur -= 3;
    }
    // ===== odd tile t+1: read A slot1, load->arO (A(t+3)), write arE (A(t+2))
    {
      const int to = t + 1;
      const unsigned short* Ard = &Asm_[1][0];
      unsigned short*       Awr = &Asm_[0][0];
      const unsigned short* Brd = &Bsm_[0][0] + scur * (BN * BK);
      int sst = scur + 2; if (sst >= 3) sst -= 3;
      unsigned short*       Bst = &Bsm_[0][0] + sst * (BN * BK);
      const bool dl = (to + 2 < NT);
      const bool dw = (to + 1 < NT);       // write A(t+2) only if it exists
      do_phase(Ard, Brd, 0, [&] {
        if (dl) { loadAg(to + 2, 0, arO[0], arO[1]); loadAg(to + 2, 1, arO[2], arO[3]);
                  stageBg(to + 2, Bst, 0); }
        if (dw) { writeAg(Awr, 0, arE[0], arE[1]); writeAg(Awr, 1, arE[2], arE[3]); }
      });
      __builtin_amdgcn_s_barrier();
      do_phase(Ard, Brd, 1, [&] {
        if (dl) { loadAg(to + 2, 2, arO[4], arO[5]); loadAg(to + 2, 3, arO[6], arO[7]);
                  stageBg(to + 2, Bst, 1); }
        if (dw) { writeAg(Awr, 2, arE[4], arE[5]); writeAg(Awr, 3, arE[6], arE[7]); }
      });
      if (to + 1 < NT) {
        if (dl) asm volatile("s_waitcnt vmcnt(10)" ::: "memory");
        else    asm volatile("s_waitcnt vmcnt(0)"  ::: "memory");
        __builtin_amdgcn_sched_barrier(0);
        __builtin_amdgcn_s_barrier();
        __builtin_amdgcn_sched_barrier(0);
      }
      scur = scur + 1; if (scur >= 3) scur -= 3;
    }
  }

  // ---- epilogue: C/D layout col=lane&15, row=(lane>>4)*4+reg --------------
  const int crow = row0 + wr * 64 + qtr * 4;
  const int ccol = col0 + wc * 64 + rb;
#pragma unroll
  for (int n = 0; n < 4; ++n) {
    int c = ccol + n * 16;
    float bv = bias[c];
#pragma unroll
    for (int m = 0; m < 4; ++m)
#pragma unroll
      for (int v = 0; v < 4; ++v)
        out[(size_t)(crow + m * 16 + v) * NDIM + c] = acc[m][n][v] + bv;
  }
}

// ---------------------------------------------------------------------------
// Workspace-free fallback (slow but correct)
// ---------------------------------------------------------------------------
__global__ void fallback_kernel(const float* __restrict__ x, const float* __restrict__ A,
                                const float* __restrict__ fB, const float* __restrict__ bias,
                                float* __restrict__ out) {
  __shared__ float xrow[1024];
  const int n = blockIdx.x;
  const int tid = threadIdx.x;
  for (int t = tid; t < 1024; t += 256) xrow[t] = x[(size_t)n * 1024 + t];
  __syncthreads();
  for (int pp = 0; pp < 4; ++pp) {
    int p = pp * 256 + tid;
    int k = p >> 6, j = p & 63;
    int kb = k >> 2, ks = k & 3;
    float accv = 0.f;
    for (int s = 0; s < 16; ++s) {
      int sb = s >> 2, ss = s & 3;
      int comp = c_comp[kb][sb];
      float sgn = c_sign[kb][sb];
      float hA[RANKS];
#pragma unroll
      for (int r = 0; r < RANKS; ++r) hA[r] = sgn * A[r * 64 + comp * 16 + ks * 4 + ss];
      for (int i = 0; i < 64; ++i) {
        float w = 0.f;
#pragma unroll
        for (int r = 0; r < RANKS; ++r) w += hA[r] * fB[r * 4096 + j * 64 + i];
        accv += xrow[s * 64 + i] * w;
      }
    }
    out[(size_t)n * 1024 + p] = accv + bias[p];
  }
}

extern "C" void kernel_launch(void* const* d_in, const int* in_sizes, int n_in,
                              void* d_out, int out_size, void* d_ws, size_t ws_size,
                              hipStream_t stream) {
  const float* x    = (const float*)d_in[0];
  const float* A    = (const float*)d_in[1];
  const float* fB   = (const float*)d_in[2];
  const float* bias = (const float*)d_in[3];
  float* out = (float*)d_out;

  const size_t needW = (size_t)NDIM * KDIM * sizeof(unsigned short);
  if (ws_size >= needW) {
    unsigned short* W = (unsigned short*)d_ws;
    build_W<<<dim3(1024), dim3(256), 0, stream>>>(A, fB, W);
    gemm_ham<<<dim3((MDIM / BM) * (NDIM / BN)), dim3(THREADS), 0, stream>>>(x, W, bias, out);
  } else {
    fallback_kernel<<<dim3(MDIM), dim3(256), 0, stream>>>(x, A, fB, bias, out);
  }
}

// Round 5
// 40.522 us; speedup vs baseline: 1.1684x; 1.1684x over previous
//
#include <hip/hip_runtime.h>
#include <stdint.h>

#define RANKS 8
#define MDIM 8192   // B*T*D / 1024 rows
#define KDIM 1024
#define NDIM 1024
#define BM 256
#define BN 128
#define BK 64
#define NT (KDIM / BK)   // 16
#define THREADS 512

typedef __bf16 bf16x8 __attribute__((ext_vector_type(8)));
typedef float f32x4 __attribute__((ext_vector_type(4)));

__device__ __forceinline__ unsigned short f2bf(float f) {
  union { float f; uint32_t u; } v; v.f = f;
  uint32_t u = v.u;
  u += 0x7FFFu + ((u >> 16) & 1u);   // round-to-nearest-even
  return (unsigned short)(u >> 16);
}

// Hamilton block tables
__constant__ int   c_comp[4][4] = {{0,1,2,3},{1,0,3,2},{2,3,0,1},{3,2,1,0}};
__constant__ float c_sign[4][4] = {{1.f,-1.f,-1.f,-1.f},
                                   {1.f, 1.f,-1.f, 1.f},
                                   {1.f, 1.f, 1.f,-1.f},
                                   {1.f,-1.f, 1.f, 1.f}};

// ---------------------------------------------------------------------------
// W[p][q] = sum_r H[r,k,s] * fB[r,j,i],  p = k*64+j, q = s*64+i.  bf16 out.
// ---------------------------------------------------------------------------
__global__ void build_W(const float* __restrict__ A, const float* __restrict__ fB,
                        unsigned short* __restrict__ W) {
  int idx = blockIdx.x * 256 + threadIdx.x;
  int p  = idx >> 8;
  int q4 = (idx & 255) << 2;
  int k = p >> 6, j = p & 63;
  int kb = k >> 2, ks = k & 3;
  int s = q4 >> 6;
  int sb = s >> 2, ss = s & 3;
  int   comp = c_comp[kb][sb];
  float sgn  = c_sign[kb][sb];
  float o0 = 0.f, o1 = 0.f, o2 = 0.f, o3 = 0.f;
  int i0 = q4 & 63;
#pragma unroll
  for (int r = 0; r < RANKS; ++r) {
    float h = sgn * A[r * 64 + comp * 16 + ks * 4 + ss];
    const float* fb = fB + r * 4096 + j * 64 + i0;
    o0 += h * fb[0]; o1 += h * fb[1]; o2 += h * fb[2]; o3 += h * fb[3];
  }
  ushort4 st;
  st.x = f2bf(o0); st.y = f2bf(o1); st.z = f2bf(o2); st.w = f2bf(o3);
  *reinterpret_cast<ushort4*>(W + (size_t)p * KDIM + q4) = st;
}

// ---------------------------------------------------------------------------
// x (f32) -> bf16, XCD-aligned so the bf16 image lands in the L2 of the XCD
// whose GEMM blocks will read it.  cvt block b -> chunk i = (b&7)*512 + b>>3:
// XCD x (dispatch round-robin b%8) writes x-panels [4x, 4x+4), matching the
// GEMM's T1 swizzle (bx = xg*4 + ...).
// ---------------------------------------------------------------------------
__global__ void cvt_x(const float* __restrict__ x, unsigned short* __restrict__ xb) {
  int b = blockIdx.x;
  int i = (b & 7) * 512 + (b >> 3);          // 4096 blocks, bijective remap
  size_t base = ((size_t)i * 256 + threadIdx.x) * 8;
  float4 a = *reinterpret_cast<const float4*>(x + base);
  float4 c = *reinterpret_cast<const float4*>(x + base + 4);
  bf16x8 v;
  v[0] = (__bf16)a.x; v[1] = (__bf16)a.y; v[2] = (__bf16)a.z; v[3] = (__bf16)a.w;
  v[4] = (__bf16)c.x; v[5] = (__bf16)c.y; v[6] = (__bf16)c.z; v[7] = (__bf16)c.w;
  *reinterpret_cast<bf16x8*>(xb + base) = v;
}

// ---------------------------------------------------------------------------
// m201-template GEMM: out = Xb * W^T + bias   (both operands bf16 in HBM/L2)
// 3-slot LDS rings, stage t+2 while computing t, vmcnt(6) once per K-tile.
// ---------------------------------------------------------------------------
__device__ __forceinline__ void gload16(const unsigned short* g, unsigned short* l) {
  __builtin_amdgcn_global_load_lds(
      (const __attribute__((address_space(1))) unsigned int*)(uintptr_t)g,
      (__attribute__((address_space(3))) unsigned int*)(uintptr_t)l,
      16, 0, 0);
}

#define SWZ(r, cbyte) (((r) * 128) + ((cbyte) ^ (((r) & 7) << 4)))

__global__ __launch_bounds__(THREADS, 2) void gemm_ham(
    const unsigned short* __restrict__ Xb, const unsigned short* __restrict__ W,
    const float* __restrict__ bias, float* __restrict__ out) {
  __shared__ unsigned short Asm_[3][BM * BK];   // 96 KB, 3-slot ring
  __shared__ unsigned short Bsm_[3][BN * BK];   // 48 KB, 3-slot ring

  const int tid  = threadIdx.x;
  const int lane = tid & 63;
  const int wid  = tid >> 6;
  const int wr   = wid >> 1;        // 0..3 (M)
  const int wc   = wid & 1;         // 0..1 (N)
  const int rb   = lane & 15;
  const int qtr  = lane >> 4;

  // T1: XCD-chunked swizzle; XCD xg owns A-panels [4*xg, 4*xg+4) x all 8 by.
  const int flat = blockIdx.x;
  const int xg = flat & 7, ig = flat >> 3;
  const int bx = xg * 4 + (ig >> 3);   // 0..31
  const int by = ig & 7;               // 0..7
  const int row0 = bx * BM;
  const int col0 = by * BN;

  f32x4 acc[4][4];
  f32x4 zero = {0.f, 0.f, 0.f, 0.f};
#pragma unroll
  for (int m = 0; m < 4; ++m)
#pragma unroll
    for (int n = 0; n < 4; ++n) acc[m][n] = zero;

  // staging: linear LDS dest + inverse-swizzled global source (rule 21)
  auto stageA = [&](int kt, int slot, int g) {
    int id = g * 512 + tid;            // 16B unit id, 0..2047
    int r = id >> 3, ct = id & 7;
    gload16(Xb + (size_t)(row0 + r) * KDIM + kt * BK + ((ct ^ (r & 7)) << 3),
            &Asm_[slot][id * 8]);
  };
  auto stageB = [&](int kt, int slot, int g) {
    int id = g * 512 + tid;            // 0..1023
    int r = id >> 3, ct = id & 7;
    gload16(W + (size_t)(col0 + r) * KDIM + kt * BK + ((ct ^ (r & 7)) << 3),
            &Bsm_[slot][id * 8]);
  };

  // one phase: 8 ds_read_b128 | 3 gload_lds | barrier | lgkm0 | 16 MFMA
  auto phase = [&](const char* Ab, const char* Bb, int kk, int t2, int slot2,
                   bool dl, int half) {
    bf16x8 af[4], bfr[4];
    const int cb = qtr * 16 + kk * 64;
#pragma unroll
    for (int m = 0; m < 4; ++m)
      af[m] = *reinterpret_cast<const bf16x8*>(Ab + SWZ(wr * 64 + m * 16 + rb, cb));
#pragma unroll
    for (int n = 0; n < 4; ++n)
      bfr[n] = *reinterpret_cast<const bf16x8*>(Bb + SWZ(wc * 64 + n * 16 + rb, cb));
    if (dl) {
      if (half == 0) { stageA(t2, slot2, 0); stageA(t2, slot2, 1); stageB(t2, slot2, 0); }
      else           { stageA(t2, slot2, 2); stageA(t2, slot2, 3); stageB(t2, slot2, 1); }
    }
    __builtin_amdgcn_sched_barrier(0);
    __builtin_amdgcn_s_barrier();
    asm volatile("s_waitcnt lgkmcnt(0)" ::: "memory");
    __builtin_amdgcn_sched_barrier(0);
    __builtin_amdgcn_s_setprio(1);
#pragma unroll
    for (int m = 0; m < 4; ++m)
#pragma unroll
      for (int n = 0; n < 4; ++n)
        acc[m][n] = __builtin_amdgcn_mfma_f32_16x16x32_bf16(af[m], bfr[n], acc[m][n], 0, 0, 0);
    __builtin_amdgcn_s_setprio(0);
    __builtin_amdgcn_sched_barrier(0);
  };

  // ---- prologue: stage tiles 0 and 1 (12 vm ops), wait for tile 0 ---------
  stageA(0, 0, 0); stageA(0, 0, 1); stageA(0, 0, 2); stageA(0, 0, 3);
  stageB(0, 0, 0); stageB(0, 0, 1);
  stageA(1, 1, 0); stageA(1, 1, 1); stageA(1, 1, 2); stageA(1, 1, 3);
  stageB(1, 1, 0); stageB(1, 1, 1);
  asm volatile("s_waitcnt vmcnt(6)" ::: "memory");   // tile 0 landed; tile 1 in flight
  __builtin_amdgcn_sched_barrier(0);
  __builtin_amdgcn_s_barrier();
  __builtin_amdgcn_sched_barrier(0);

  // ---- main loop ----------------------------------------------------------
  int sc = 0;                                        // read slot = t % 3
#pragma unroll 1
  for (int t = 0; t < NT; ++t) {
    const char* Ab = reinterpret_cast<const char*>(&Asm_[sc][0]);
    const char* Bb = reinterpret_cast<const char*>(&Bsm_[sc][0]);
    int slot2 = sc + 2; if (slot2 >= 3) slot2 -= 3;  // (t+2) % 3
    const bool dl = (t + 2 < NT);
    phase(Ab, Bb, 0, t + 2, slot2, dl, 0);
    __builtin_amdgcn_s_barrier();                    // phase separator
    phase(Ab, Bb, 1, t + 2, slot2, dl, 1);
    if (t < NT - 1) {
      if (t < NT - 2) asm volatile("s_waitcnt vmcnt(6)" ::: "memory");  // tile t+1 landed
      else            asm volatile("s_waitcnt vmcnt(0)" ::: "memory");  // final drain
      __builtin_amdgcn_sched_barrier(0);
      __builtin_amdgcn_s_barrier();                  // tile separator
      __builtin_amdgcn_sched_barrier(0);
    }
    sc = sc + 1; if (sc >= 3) sc -= 3;
  }

  // ---- epilogue: C/D layout col=lane&15, row=(lane>>4)*4+reg --------------
  const int crow = row0 + wr * 64 + qtr * 4;
  const int ccol = col0 + wc * 64 + rb;
#pragma unroll
  for (int n = 0; n < 4; ++n) {
    int c = ccol + n * 16;
    float bv = bias[c];
#pragma unroll
    for (int m = 0; m < 4; ++m)
#pragma unroll
      for (int v = 0; v < 4; ++v)
        out[(size_t)(crow + m * 16 + v) * NDIM + c] = acc[m][n][v] + bv;
  }
}

// ---------------------------------------------------------------------------
// Workspace-free fallback (slow but correct)
// ---------------------------------------------------------------------------
__global__ void fallback_kernel(const float* __restrict__ x, const float* __restrict__ A,
                                const float* __restrict__ fB, const float* __restrict__ bias,
                                float* __restrict__ out) {
  __shared__ float xrow[1024];
  const int n = blockIdx.x;
  const int tid = threadIdx.x;
  for (int t = tid; t < 1024; t += 256) xrow[t] = x[(size_t)n * 1024 + t];
  __syncthreads();
  for (int pp = 0; pp < 4; ++pp) {
    int p = pp * 256 + tid;
    int k = p >> 6, j = p & 63;
    int kb = k >> 2, ks = k & 3;
    float accv = 0.f;
    for (int s = 0; s < 16; ++s) {
      int sb = s >> 2, ss = s & 3;
      int comp = c_comp[kb][sb];
      float sgn = c_sign[kb][sb];
      float hA[RANKS];
#pragma unroll
      for (int r = 0; r < RANKS; ++r) hA[r] = sgn * A[r * 64 + comp * 16 + ks * 4 + ss];
      for (int i = 0; i < 64; ++i) {
        float w = 0.f;
#pragma unroll
        for (int r = 0; r < RANKS; ++r) w += hA[r] * fB[r * 4096 + j * 64 + i];
        accv += xrow[s * 64 + i] * w;
      }
    }
    out[(size_t)n * 1024 + p] = accv + bias[p];
  }
}

extern "C" void kernel_launch(void* const* d_in, const int* in_sizes, int n_in,
                              void* d_out, int out_size, void* d_ws, size_t ws_size,
                              hipStream_t stream) {
  const float* x    = (const float*)d_in[0];
  const float* A    = (const float*)d_in[1];
  const float* fB   = (const float*)d_in[2];
  const float* bias = (const float*)d_in[3];
  float* out = (float*)d_out;

  const size_t needW = (size_t)NDIM * KDIM * sizeof(unsigned short);
  const size_t needX = (size_t)MDIM * KDIM * sizeof(unsigned short);
  if (ws_size >= needW + needX) {
    unsigned short* W  = (unsigned short*)d_ws;
    unsigned short* Xb = W + (size_t)NDIM * KDIM;
    build_W<<<dim3(1024), dim3(256), 0, stream>>>(A, fB, W);
    cvt_x<<<dim3(4096), dim3(256), 0, stream>>>(x, Xb);
    gemm_ham<<<dim3((MDIM / BM) * (NDIM / BN)), dim3(THREADS), 0, stream>>>(Xb, W, bias, out);
  } else {
    fallback_kernel<<<dim3(MDIM), dim3(256), 0, stream>>>(x, A, fB, bias, out);
  }
}

// Round 6
// 37.266 us; speedup vs baseline: 1.2704x; 1.0874x over previous
//
#include <hip/hip_runtime.h>
#include <stdint.h>

#define RANKS 8
#define MDIM 8192   // B*T*D / 1024 rows
#define KDIM 1024
#define NDIM 1024
#define BM 128
#define BN 128
#define BK 32
#define NT (KDIM / BK)   // 32
#define THREADS 256

typedef __bf16 bf16x8 __attribute__((ext_vector_type(8)));
typedef float f32x4 __attribute__((ext_vector_type(4)));

__device__ __forceinline__ unsigned short f2bf(float f) {
  union { float f; uint32_t u; } v; v.f = f;
  uint32_t u = v.u;
  u += 0x7FFFu + ((u >> 16) & 1u);   // round-to-nearest-even
  return (unsigned short)(u >> 16);
}

// Hamilton block tables
__constant__ int   c_comp[4][4] = {{0,1,2,3},{1,0,3,2},{2,3,0,1},{3,2,1,0}};
__constant__ float c_sign[4][4] = {{1.f,-1.f,-1.f,-1.f},
                                   {1.f, 1.f,-1.f, 1.f},
                                   {1.f, 1.f, 1.f,-1.f},
                                   {1.f,-1.f, 1.f, 1.f}};

// ---------------------------------------------------------------------------
// W[p][q] = sum_r H[r,k,s] * fB[r,j,i],  p = k*64+j, q = s*64+i.  bf16 out.
// ---------------------------------------------------------------------------
__global__ void build_W(const float* __restrict__ A, const float* __restrict__ fB,
                        unsigned short* __restrict__ W) {
  int idx = blockIdx.x * 256 + threadIdx.x;
  int p  = idx >> 8;
  int q4 = (idx & 255) << 2;
  int k = p >> 6, j = p & 63;
  int kb = k >> 2, ks = k & 3;
  int s = q4 >> 6;
  int sb = s >> 2, ss = s & 3;
  int   comp = c_comp[kb][sb];
  float sgn  = c_sign[kb][sb];
  float o0 = 0.f, o1 = 0.f, o2 = 0.f, o3 = 0.f;
  int i0 = q4 & 63;
#pragma unroll
  for (int r = 0; r < RANKS; ++r) {
    float h = sgn * A[r * 64 + comp * 16 + ks * 4 + ss];
    const float* fb = fB + r * 4096 + j * 64 + i0;
    o0 += h * fb[0]; o1 += h * fb[1]; o2 += h * fb[2]; o3 += h * fb[3];
  }
  ushort4 st;
  st.x = f2bf(o0); st.y = f2bf(o1); st.z = f2bf(o2); st.w = f2bf(o3);
  *reinterpret_cast<ushort4*>(W + (size_t)p * KDIM + q4) = st;
}

// ---------------------------------------------------------------------------
// Fused GEMM: out = bf16(x) * W^T + bias.
// A staged as *f32* via global_load_lds (async DMA, no reg round-trip);
// frag-read as f32 + in-register cvt to bf16. B staged as bf16 from W.
// 3-slot rings, stage t+2, vmcnt(6) per tile (single vmcnt(0) at drain).
// 72 KB LDS -> 2 blocks/CU for cross-block latency hiding.
// ---------------------------------------------------------------------------
__device__ __forceinline__ void gload16(const void* g, void* l) {
  __builtin_amdgcn_global_load_lds(
      (const __attribute__((address_space(1))) unsigned int*)(uintptr_t)g,
      (__attribute__((address_space(3))) unsigned int*)(uintptr_t)l,
      16, 0, 0);
}

__global__ __launch_bounds__(THREADS, 2) void gemm_ham(
    const float* __restrict__ x, const unsigned short* __restrict__ W,
    const float* __restrict__ bias, float* __restrict__ out) {
  __shared__ float          Asm_[3][BM * BK];   // f32: 16 KB/slot, 48 KB
  __shared__ unsigned short Bsm_[3][BN * BK];   // bf16: 8 KB/slot, 24 KB

  const int tid  = threadIdx.x;
  const int lane = tid & 63;
  const int wid  = tid >> 6;        // 0..3
  const int wr   = wid >> 1;        // 0..1 (M)
  const int wc   = wid & 1;         // 0..1 (N)
  const int rb   = lane & 15;
  const int qtr  = lane >> 4;       // 0..3

  // T1: XCD-chunked bijective swizzle over 512 blocks (8 XCDs x 64).
  // XCD xg owns A-row-panels [8*xg, 8*xg+8) x all 8 col-blocks.
  const int flat = blockIdx.x;
  const int xg = flat & 7, ig = flat >> 3;     // ig: 0..63
  const int bx = xg * 8 + (ig >> 3);           // 0..63
  const int by = ig & 7;                       // 0..7
  const int row0 = bx * BM;
  const int col0 = by * BN;

  f32x4 acc[4][4];
  f32x4 zero = {0.f, 0.f, 0.f, 0.f};
#pragma unroll
  for (int m = 0; m < 4; ++m)
#pragma unroll
    for (int n = 0; n < 4; ++n) acc[m][n] = zero;

  // ---- staging (async DMA; linear LDS dest, A source inverse-swizzled) ----
  // A slot: [128 rows][32 f32] = 128 B/row = 8x16B units. Swizzle u^(r&7).
  auto stageA = [&](int kt, int slot) {
#pragma unroll
    for (int g = 0; g < 4; ++g) {
      int id = g * 256 + tid;        // 16B-unit id, 0..1023
      int r = id >> 3, ct = id & 7;
      gload16(x + (size_t)(row0 + r) * KDIM + kt * BK + ((ct ^ (r & 7)) << 2),
              &Asm_[slot][id * 4]);
    }
  };
  // B slot: [128 rows][32 bf16] = 64 B/row = 4x16B units. No swizzle needed.
  auto stageB = [&](int kt, int slot) {
#pragma unroll
    for (int g = 0; g < 2; ++g) {
      int id = g * 256 + tid;        // 0..511
      int r = id >> 2, ct = id & 3;
      gload16(W + (size_t)(col0 + r) * KDIM + kt * BK + (ct << 3),
              &Bsm_[slot][id * 8]);
    }
  };

  // ---- prologue: stage tiles 0,1 (12 vm ops); wait tile 0 (6 left) --------
  stageA(0, 0); stageB(0, 0);
  stageA(1, 1); stageB(1, 1);
  asm volatile("s_waitcnt vmcnt(6)" ::: "memory");
  __builtin_amdgcn_sched_barrier(0);
  __builtin_amdgcn_s_barrier();
  __builtin_amdgcn_sched_barrier(0);

  // ---- main loop: 1 tile = 1 phase (16 MFMA), counted-vmcnt ring ----------
  int sc = 0;
#pragma unroll 1
  for (int t = 0; t < NT; ++t) {
    int s2 = sc + 2; if (s2 >= 3) s2 -= 3;
    if (t + 2 < NT) { stageA(t + 2, s2); stageB(t + 2, s2); }  // fly under MFMA

    const char* Ab = reinterpret_cast<const char*>(&Asm_[sc][0]);
    const char* Bb = reinterpret_cast<const char*>(&Bsm_[sc][0]);
    bf16x8 af[4], bfr[4];
#pragma unroll
    for (int m = 0; m < 4; ++m) {
      int r = wr * 64 + m * 16 + rb;
      int u0 = (qtr * 2)     ^ (r & 7);
      int u1 = (qtr * 2 + 1) ^ (r & 7);
      f32x4 lo = *reinterpret_cast<const f32x4*>(Ab + r * 128 + (u0 << 4));
      f32x4 hi = *reinterpret_cast<const f32x4*>(Ab + r * 128 + (u1 << 4));
      bf16x8 v;
      v[0] = (__bf16)lo[0]; v[1] = (__bf16)lo[1]; v[2] = (__bf16)lo[2]; v[3] = (__bf16)lo[3];
      v[4] = (__bf16)hi[0]; v[5] = (__bf16)hi[1]; v[6] = (__bf16)hi[2]; v[7] = (__bf16)hi[3];
      af[m] = v;
    }
#pragma unroll
    for (int n = 0; n < 4; ++n) {
      int r = wc * 64 + n * 16 + rb;
      bfr[n] = *reinterpret_cast<const bf16x8*>(Bb + r * 64 + qtr * 16);
    }

    __builtin_amdgcn_s_setprio(1);
#pragma unroll
    for (int m = 0; m < 4; ++m)
#pragma unroll
      for (int n = 0; n < 4; ++n)
        acc[m][n] = __builtin_amdgcn_mfma_f32_16x16x32_bf16(af[m], bfr[n], acc[m][n], 0, 0, 0);
    __builtin_amdgcn_s_setprio(0);

    if (t < NT - 1) {
      if (t < NT - 2) asm volatile("s_waitcnt vmcnt(6)" ::: "memory");  // t+1 landed
      else            asm volatile("s_waitcnt vmcnt(0)" ::: "memory");  // final drain
      __builtin_amdgcn_sched_barrier(0);
      __builtin_amdgcn_s_barrier();
      __builtin_amdgcn_sched_barrier(0);
    }
    sc = sc + 1; if (sc >= 3) sc -= 3;
  }

  // ---- epilogue: C/D layout col=lane&15, row=(lane>>4)*4+reg --------------
  const int crow = row0 + wr * 64 + qtr * 4;
  const int ccol = col0 + wc * 64 + rb;
#pragma unroll
  for (int n = 0; n < 4; ++n) {
    int c = ccol + n * 16;
    float bv = bias[c];
#pragma unroll
    for (int m = 0; m < 4; ++m)
#pragma unroll
      for (int v = 0; v < 4; ++v)
        out[(size_t)(crow + m * 16 + v) * NDIM + c] = acc[m][n][v] + bv;
  }
}

// ---------------------------------------------------------------------------
// Workspace-free fallback (slow but correct)
// ---------------------------------------------------------------------------
__global__ void fallback_kernel(const float* __restrict__ x, const float* __restrict__ A,
                                const float* __restrict__ fB, const float* __restrict__ bias,
                                float* __restrict__ out) {
  __shared__ float xrow[1024];
  const int n = blockIdx.x;
  const int tid = threadIdx.x;
  for (int t = tid; t < 1024; t += 256) xrow[t] = x[(size_t)n * 1024 + t];
  __syncthreads();
  for (int pp = 0; pp < 4; ++pp) {
    int p = pp * 256 + tid;
    int k = p >> 6, j = p & 63;
    int kb = k >> 2, ks = k & 3;
    float accv = 0.f;
    for (int s = 0; s < 16; ++s) {
      int sb = s >> 2, ss = s & 3;
      int comp = c_comp[kb][sb];
      float sgn = c_sign[kb][sb];
      float hA[RANKS];
#pragma unroll
      for (int r = 0; r < RANKS; ++r) hA[r] = sgn * A[r * 64 + comp * 16 + ks * 4 + ss];
      for (int i = 0; i < 64; ++i) {
        float w = 0.f;
#pragma unroll
        for (int r = 0; r < RANKS; ++r) w += hA[r] * fB[r * 4096 + j * 64 + i];
        accv += xrow[s * 64 + i] * w;
      }
    }
    out[(size_t)n * 1024 + p] = accv + bias[p];
  }
}

extern "C" void kernel_launch(void* const* d_in, const int* in_sizes, int n_in,
                              void* d_out, int out_size, void* d_ws, size_t ws_size,
                              hipStream_t stream) {
  const float* x    = (const float*)d_in[0];
  const float* A    = (const float*)d_in[1];
  const float* fB   = (const float*)d_in[2];
  const float* bias = (const float*)d_in[3];
  float* out = (float*)d_out;

  const size_t needW = (size_t)NDIM * KDIM * sizeof(unsigned short);
  if (ws_size >= needW) {
    unsigned short* W = (unsigned short*)d_ws;
    build_W<<<dim3(1024), dim3(256), 0, stream>>>(A, fB, W);
    gemm_ham<<<dim3((MDIM / BM) * (NDIM / BN)), dim3(THREADS), 0, stream>>>(x, W, bias, out);
  } else {
    fallback_kernel<<<dim3(MDIM), dim3(256), 0, stream>>>(x, A, fB, bias, out);
  }
}